// Round 1
// baseline (270.132 us; speedup 1.0000x reference)
//
#include <hip/hip_runtime.h>

#define NPTS 1024
#define NN (NPTS * NPTS)
#define NEDGE 32768
#define INDIM 128

// ---------------- small kernels ----------------

__global__ void zero_kernel(float4* __restrict__ p, int n4) {
    int i = blockIdx.x * blockDim.x + threadIdx.x;
    if (i < n4) p[i] = make_float4(0.f, 0.f, 0.f, 0.f);
}

// one wave (64 lanes) per node: p[n] = dot(features[n], w) + b
__global__ void compute_p_kernel(const float* __restrict__ feat,
                                 const float* __restrict__ w,
                                 const float* __restrict__ b,
                                 float* __restrict__ p) {
    int node = blockIdx.x * (blockDim.x >> 6) + (threadIdx.x >> 6);
    int lane = threadIdx.x & 63;
    const float* f = feat + node * INDIM;
    float s = f[lane] * w[lane] + f[lane + 64] * w[lane + 64];
#pragma unroll
    for (int off = 32; off; off >>= 1) s += __shfl_down(s, off);
    if (lane == 0) p[node] = s + b[0];
}

__global__ void build_A_kernel(const int* __restrict__ eu, const int* __restrict__ ev,
                               const float* __restrict__ p, float* __restrict__ A) {
    int i = blockIdx.x * blockDim.x + threadIdx.x;
    if (i >= NEDGE) return;
    int u = eu[i], v = ev[i];
    float val = p[u] - p[v];
    if (val > 0.f) {
        float w = 1.f + val;
        atomicAdd(&A[u * NPTS + v], w);
        atomicAdd(&A[v * NPTS + u], w);
    } else {
        atomicAdd(&A[u * NPTS + u], 1.f);
        atomicAdd(&A[v * NPTS + v], 1.f);
    }
}

__global__ void add_eye_kernel(float* __restrict__ A) {
    int i = blockIdx.x * blockDim.x + threadIdx.x;
    if (i < NPTS) A[i * NPTS + i] += 1.f;
}

// per-row sum -> dinv = rsqrt(d)   (d >= 1 always, diag has the eye)
__global__ void row_deg_kernel(const float* __restrict__ A, float* __restrict__ dinv) {
    int row = blockIdx.x;
    float s = 0.f;
    for (int j = threadIdx.x; j < NPTS; j += blockDim.x) s += A[row * NPTS + j];
    __shared__ float red[8];
    int lane = threadIdx.x & 63, wid = threadIdx.x >> 6;
#pragma unroll
    for (int off = 32; off; off >>= 1) s += __shfl_down(s, off);
    if (lane == 0) red[wid] = s;
    __syncthreads();
    if (threadIdx.x == 0) {
        float t = 0.f;
        for (int w = 0; w < (int)(blockDim.x >> 6); ++w) t += red[w];
        dinv[row] = rsqrtf(t);
    }
}

// write T0 = I and T1 = -(dinv_i * A_ij * dinv_j)
__global__ void normalize_kernel(const float* __restrict__ A, const float* __restrict__ dinv,
                                 float* __restrict__ out) {
    int idx = blockIdx.x * blockDim.x + threadIdx.x;
    int i = idx >> 10, j = idx & (NPTS - 1);
    float m = -(dinv[i] * A[idx] * dinv[j]);
    out[idx] = (i == j) ? 1.f : 0.f;  // T0
    out[NN + idx] = m;                // T1
}

// ---------------- fp32 tiled GEMM: C = 2*Mm*B - Cprev ----------------
#define BM 64
#define BN 64
#define BK 16

__global__ __launch_bounds__(256) void cheb_gemm_kernel(const float* __restrict__ Mm,
                                                        const float* __restrict__ B,
                                                        const float* __restrict__ Cprev,
                                                        float* __restrict__ C) {
    __shared__ float sA[BK][BM + 1];  // stored transposed: sA[k][m]
    __shared__ float sB[BK][BN + 1];
    int tid = threadIdx.x;
    int brow = blockIdx.y * BM, bcol = blockIdx.x * BN;
    int tr = (tid >> 4) * 4;  // 0..60
    int tc = (tid & 15) * 4;  // 0..60
    float acc[4][4] = {};

    for (int k0 = 0; k0 < NPTS; k0 += BK) {
        // A tile 64x16: linear l = r*16 + c, thread loads 4 consecutive c
        {
            int l = tid * 4;
            int r = l >> 4;
            int c = l & 15;
            float4 vv = *reinterpret_cast<const float4*>(&Mm[(brow + r) * NPTS + k0 + c]);
            sA[c + 0][r] = vv.x; sA[c + 1][r] = vv.y; sA[c + 2][r] = vv.z; sA[c + 3][r] = vv.w;
        }
        // B tile 16x64: linear l = k*64 + c
        {
            int l = tid * 4;
            int k = l >> 6;
            int c = l & 63;
            float4 vv = *reinterpret_cast<const float4*>(&B[(k0 + k) * NPTS + bcol + c]);
            sB[k][c + 0] = vv.x; sB[k][c + 1] = vv.y; sB[k][c + 2] = vv.z; sB[k][c + 3] = vv.w;
        }
        __syncthreads();
#pragma unroll
        for (int kk = 0; kk < BK; ++kk) {
            float a0 = sA[kk][tr + 0], a1 = sA[kk][tr + 1], a2 = sA[kk][tr + 2], a3 = sA[kk][tr + 3];
            float b0 = sB[kk][tc + 0], b1 = sB[kk][tc + 1], b2 = sB[kk][tc + 2], b3 = sB[kk][tc + 3];
            acc[0][0] += a0 * b0; acc[0][1] += a0 * b1; acc[0][2] += a0 * b2; acc[0][3] += a0 * b3;
            acc[1][0] += a1 * b0; acc[1][1] += a1 * b1; acc[1][2] += a1 * b2; acc[1][3] += a1 * b3;
            acc[2][0] += a2 * b0; acc[2][1] += a2 * b1; acc[2][2] += a2 * b2; acc[2][3] += a2 * b3;
            acc[3][0] += a3 * b0; acc[3][1] += a3 * b1; acc[3][2] += a3 * b2; acc[3][3] += a3 * b3;
        }
        __syncthreads();
    }
#pragma unroll
    for (int r2 = 0; r2 < 4; ++r2) {
        int gi = brow + tr + r2;
        float4 cp = *reinterpret_cast<const float4*>(&Cprev[gi * NPTS + bcol + tc]);
        float4 o;
        o.x = 2.f * acc[r2][0] - cp.x;
        o.y = 2.f * acc[r2][1] - cp.y;
        o.z = 2.f * acc[r2][2] - cp.z;
        o.w = 2.f * acc[r2][3] - cp.w;
        *reinterpret_cast<float4*>(&C[gi * NPTS + bcol + tc]) = o;
    }
}

// ---------------- launch ----------------

extern "C" void kernel_launch(void* const* d_in, const int* in_sizes, int n_in,
                              void* d_out, int out_size, void* d_ws, size_t ws_size,
                              hipStream_t stream) {
    const float* feat = (const float*)d_in[0];
    const int* edges = (const int*)d_in[1];  // [2, 32768] int32
    const float* w_e1 = (const float*)d_in[2];
    const float* b_e1 = (const float*)d_in[3];
    float* out = (float*)d_out;

    // layout: out[0..5NN) = T0..T4 (real).  out[5NN..10NN) = imag (all zero).
    // Scratch inside the imag region (it gets zeroed at the end):
    float* A = out + (size_t)5 * NN;          // NN floats
    float* p = out + (size_t)6 * NN;          // NPTS floats
    float* dinv = out + (size_t)6 * NN + NPTS;  // NPTS floats

    // 1. zero A
    zero_kernel<<<NN / 4 / 256, 256, 0, stream>>>((float4*)A, NN / 4);
    // 2. p
    compute_p_kernel<<<NPTS / 4, 256, 0, stream>>>(feat, w_e1, b_e1, p);
    // 3. scatter edges
    build_A_kernel<<<(NEDGE + 255) / 256, 256, 0, stream>>>(edges, edges + NEDGE, p, A);
    // 4. + eye
    add_eye_kernel<<<(NPTS + 255) / 256, 256, 0, stream>>>(A);
    // 5. degrees
    row_deg_kernel<<<NPTS, 256, 0, stream>>>(A, dinv);
    // 6. T0 = I, T1 = -A_norm
    normalize_kernel<<<NN / 256, 256, 0, stream>>>(A, dinv, out);
    // 7. Chebyshev GEMMs: T_k = 2*M*T_{k-1} - T_{k-2}, M = T1
    dim3 grid(NPTS / BN, NPTS / BM);
    const float* Mm = out + NN;
    cheb_gemm_kernel<<<grid, 256, 0, stream>>>(Mm, out + NN, out, out + (size_t)2 * NN);
    cheb_gemm_kernel<<<grid, 256, 0, stream>>>(Mm, out + (size_t)2 * NN, out + NN, out + (size_t)3 * NN);
    cheb_gemm_kernel<<<grid, 256, 0, stream>>>(Mm, out + (size_t)3 * NN, out + (size_t)2 * NN, out + (size_t)4 * NN);
    // 8. zero the entire imag half (also wipes A/p/dinv scratch)
    zero_kernel<<<(5 * NN / 4 + 255) / 256, 256, 0, stream>>>((float4*)(out + (size_t)5 * NN), 5 * NN / 4);
}

// Round 2
// 67.606 us; speedup vs baseline: 3.9957x; 3.9957x over previous
//
#include <hip/hip_runtime.h>

#define NPTS 1024
#define NN (NPTS * NPTS)
#define NEDGE 32768
#define INDIM 128

typedef __attribute__((ext_vector_type(4))) short bf16x4;
typedef __attribute__((ext_vector_type(4))) float f32x4;

__device__ inline ushort f2bf(float x) {
    union { float f; unsigned u; } v; v.f = x;
    unsigned r = (v.u + 0x7FFF + ((v.u >> 16) & 1)) >> 16;
    return (ushort)r;
}

__device__ inline f32x4 mfma16(bf16x4 a, bf16x4 b, f32x4 c) {
#if __has_builtin(__builtin_amdgcn_mfma_f32_16x16x16bf16_1k)
    return __builtin_amdgcn_mfma_f32_16x16x16bf16_1k(a, b, c, 0, 0, 0);
#else
    f32x4 d;
    asm volatile("v_mfma_f32_16x16x16_bf16 %0, %1, %2, %3"
                 : "=v"(d) : "v"(a), "v"(b), "v"(c));
    return d;
#endif
}

// ---------------- small kernels ----------------

__global__ void zero_kernel(float4* __restrict__ p, int n4) {
    int i = blockIdx.x * blockDim.x + threadIdx.x;
    if (i < n4) p[i] = make_float4(0.f, 0.f, 0.f, 0.f);
}

// one wave (64 lanes) per node: p[n] = dot(features[n], w) + b
__global__ void compute_p_kernel(const float* __restrict__ feat,
                                 const float* __restrict__ w,
                                 const float* __restrict__ b,
                                 float* __restrict__ p) {
    int node = blockIdx.x * (blockDim.x >> 6) + (threadIdx.x >> 6);
    int lane = threadIdx.x & 63;
    const float* f = feat + node * INDIM;
    float s = f[lane] * w[lane] + f[lane + 64] * w[lane + 64];
#pragma unroll
    for (int off = 32; off; off >>= 1) s += __shfl_down(s, off);
    if (lane == 0) p[node] = s + b[0];
}

__global__ void build_A_kernel(const int* __restrict__ eu, const int* __restrict__ ev,
                               const float* __restrict__ p, float* __restrict__ A) {
    int i = blockIdx.x * blockDim.x + threadIdx.x;
    if (i >= NEDGE) return;
    int u = eu[i], v = ev[i];
    float val = p[u] - p[v];
    if (val > 0.f) {
        float w = 1.f + val;
        atomicAdd(&A[u * NPTS + v], w);
        atomicAdd(&A[v * NPTS + u], w);
    } else {
        atomicAdd(&A[u * NPTS + u], 1.f);
        atomicAdd(&A[v * NPTS + v], 1.f);
    }
}

__global__ void add_eye_kernel(float* __restrict__ A) {
    int i = blockIdx.x * blockDim.x + threadIdx.x;
    if (i < NPTS) A[i * NPTS + i] += 1.f;
}

__global__ void row_deg_kernel(const float* __restrict__ A, float* __restrict__ dinv) {
    int row = blockIdx.x;
    float s = 0.f;
    for (int j = threadIdx.x; j < NPTS; j += blockDim.x) s += A[row * NPTS + j];
    __shared__ float red[8];
    int lane = threadIdx.x & 63, wid = threadIdx.x >> 6;
#pragma unroll
    for (int off = 32; off; off >>= 1) s += __shfl_down(s, off);
    if (lane == 0) red[wid] = s;
    __syncthreads();
    if (threadIdx.x == 0) {
        float t = 0.f;
        for (int w = 0; w < (int)(blockDim.x >> 6); ++w) t += red[w];
        dinv[row] = rsqrtf(t);
    }
}

// write T0 = I, T1 = M = -(dinv_i*A_ij*dinv_j) (fp32), and M in bf16
__global__ void normalize_kernel(const float* __restrict__ A, const float* __restrict__ dinv,
                                 float* __restrict__ out, ushort* __restrict__ Mbf) {
    int idx = blockIdx.x * blockDim.x + threadIdx.x;
    int i = idx >> 10, j = idx & (NPTS - 1);
    float m = -(dinv[i] * A[idx] * dinv[j]);
    out[idx] = (i == j) ? 1.f : 0.f;  // T0
    out[NN + idx] = m;                // T1
    Mbf[idx] = f2bf(m);
}

// ---------------- MFMA GEMM (bf16 in, fp32 acc) ----------------
// 64x64 tile per block, 4 waves of 32x32 (2x2 of 16x16x16 MFMA), BK=64.
// Both operands are symmetric matrices, so B[k][n] is read as row n, col k.
// mode 1: S = M*M   -> T2 = 2S - I (fp32), Sbf = bf16(S)
// mode 2: P = S*S   -> T4 = 8P - 4*T2 - 3I
// mode 3: R = M*S   -> T3 = 4R - 3*T1
__global__ __launch_bounds__(256) void cheb_mfma_kernel(const ushort* __restrict__ Mbf,
                                                        const ushort* __restrict__ Sbf,
                                                        float* __restrict__ out,
                                                        int phase) {
    int mode = (phase == 0) ? 1 : (2 + blockIdx.z);
    const ushort* Ab = (mode == 2) ? Sbf : Mbf;
    const ushort* Bb = (mode == 1) ? Mbf : Sbf;

    __shared__ ushort sA[64][72];
    __shared__ ushort sB[64][72];

    int tid = threadIdx.x;
    int brow = blockIdx.y * 64, bcol = blockIdx.x * 64;

    int r0 = tid >> 3;            // 0..31
    int j0 = (tid & 7) * 8;       // 0..56 (bf16 units)
    int r1 = r0 + 32;

    int wid = tid >> 6, lane = tid & 63;
    int wr = (wid >> 1) * 32, wc = (wid & 1) * 32;
    int fr = lane & 15, g = lane >> 4;

    f32x4 acc[2][2] = {};
    float4 pa0, pa1, pb0, pb1;

    // prefetch tile 0
    pa0 = *(const float4*)(Ab + (size_t)(brow + r0) * NPTS + j0);
    pa1 = *(const float4*)(Ab + (size_t)(brow + r1) * NPTS + j0);
    pb0 = *(const float4*)(Bb + (size_t)(bcol + r0) * NPTS + j0);
    pb1 = *(const float4*)(Bb + (size_t)(bcol + r1) * NPTS + j0);

    const int NT = NPTS / 64;
    for (int t = 0; t < NT; ++t) {
        __syncthreads();
        *(float4*)&sA[r0][j0] = pa0;
        *(float4*)&sA[r1][j0] = pa1;
        *(float4*)&sB[r0][j0] = pb0;
        *(float4*)&sB[r1][j0] = pb1;
        __syncthreads();
        if (t + 1 < NT) {
            int k0 = (t + 1) * 64;
            pa0 = *(const float4*)(Ab + (size_t)(brow + r0) * NPTS + k0 + j0);
            pa1 = *(const float4*)(Ab + (size_t)(brow + r1) * NPTS + k0 + j0);
            pb0 = *(const float4*)(Bb + (size_t)(bcol + r0) * NPTS + k0 + j0);
            pb1 = *(const float4*)(Bb + (size_t)(bcol + r1) * NPTS + k0 + j0);
        }
#pragma unroll
        for (int kc = 0; kc < 4; ++kc) {
            int kk = kc * 16 + g * 4;
            bf16x4 a0 = *(const bf16x4*)&sA[wr + fr][kk];
            bf16x4 a1 = *(const bf16x4*)&sA[wr + 16 + fr][kk];
            bf16x4 b0 = *(const bf16x4*)&sB[wc + fr][kk];
            bf16x4 b1 = *(const bf16x4*)&sB[wc + 16 + fr][kk];
            acc[0][0] = mfma16(a0, b0, acc[0][0]);
            acc[0][1] = mfma16(a0, b1, acc[0][1]);
            acc[1][0] = mfma16(a1, b0, acc[1][0]);
            acc[1][1] = mfma16(a1, b1, acc[1][1]);
        }
    }

    // epilogue
    float* T1 = out + (size_t)NN;
    float* T2 = out + (size_t)2 * NN;
    float* T3 = out + (size_t)3 * NN;
    float* T4 = out + (size_t)4 * NN;
    ushort* SbfW = (ushort*)Sbf;  // written in mode 1 only

#pragma unroll
    for (int mi = 0; mi < 2; ++mi) {
#pragma unroll
        for (int ni = 0; ni < 2; ++ni) {
#pragma unroll
            for (int q = 0; q < 4; ++q) {
                int row = brow + wr + mi * 16 + g * 4 + q;
                int col = bcol + wc + ni * 16 + fr;
                size_t idx = (size_t)row * NPTS + col;
                float s = acc[mi][ni][q];
                if (mode == 1) {
                    T2[idx] = 2.f * s - (row == col ? 1.f : 0.f);
                    SbfW[idx] = f2bf(s);
                } else if (mode == 2) {
                    T4[idx] = 8.f * s - 4.f * T2[idx] - (row == col ? 3.f : 0.f);
                } else {
                    T3[idx] = 4.f * s - 3.f * T1[idx];
                }
            }
        }
    }
}

// ---------------- launch ----------------

extern "C" void kernel_launch(void* const* d_in, const int* in_sizes, int n_in,
                              void* d_out, int out_size, void* d_ws, size_t ws_size,
                              hipStream_t stream) {
    const float* feat = (const float*)d_in[0];
    const int* edges = (const int*)d_in[1];
    const float* w_e1 = (const float*)d_in[2];
    const float* b_e1 = (const float*)d_in[3];
    float* out = (float*)d_out;

    // scratch lives in the imag half (out+5NN..out+10NN), zeroed at the end
    float* A = out + (size_t)5 * NN;                 // NN floats
    ushort* Mbf = (ushort*)(out + (size_t)6 * NN);   // NN bf16
    ushort* Sbf = Mbf + NN;                          // NN bf16 (ends at out+7NN)
    float* p = out + (size_t)7 * NN;                 // NPTS
    float* dinv = p + NPTS;                          // NPTS

    zero_kernel<<<NN / 4 / 256, 256, 0, stream>>>((float4*)A, NN / 4);
    compute_p_kernel<<<NPTS / 4, 256, 0, stream>>>(feat, w_e1, b_e1, p);
    build_A_kernel<<<(NEDGE + 255) / 256, 256, 0, stream>>>(edges, edges + NEDGE, p, A);
    add_eye_kernel<<<(NPTS + 255) / 256, 256, 0, stream>>>(A);
    row_deg_kernel<<<NPTS, 256, 0, stream>>>(A, dinv);
    normalize_kernel<<<NN / 256, 256, 0, stream>>>(A, dinv, out, Mbf);

    dim3 grid1(16, 16, 1);
    cheb_mfma_kernel<<<grid1, 256, 0, stream>>>(Mbf, Sbf, out, 0);  // S=M*M -> T2, Sbf
    dim3 grid2(16, 16, 2);
    cheb_mfma_kernel<<<grid2, 256, 0, stream>>>(Mbf, Sbf, out, 1);  // T4 (z=0), T3 (z=1)

    zero_kernel<<<(5 * NN / 4 + 255) / 256, 256, 0, stream>>>((float4*)(out + (size_t)5 * NN), 5 * NN / 4);
}

// Round 3
// 54.142 us; speedup vs baseline: 4.9893x; 1.2487x over previous
//
#include <hip/hip_runtime.h>

#define NPTS 1024
#define NN (NPTS * NPTS)
#define NEDGE 32768
#define INDIM 128

typedef __attribute__((ext_vector_type(8))) short bf16x8;
typedef __attribute__((ext_vector_type(4))) float f32x4;

__device__ inline ushort f2bf(float x) {
    union { float f; unsigned u; } v; v.f = x;
    unsigned r = (v.u + 0x7FFF + ((v.u >> 16) & 1)) >> 16;
    return (ushort)r;
}

// ---------------- front-end kernels ----------------

// grid 1024 x 256: every block zeroes 256 float4 of A; blocks 0..255 also
// compute p for 4 nodes (one wave each).
__global__ void zeroA_p_kernel(float4* __restrict__ A4,
                               const float* __restrict__ feat,
                               const float* __restrict__ w,
                               const float* __restrict__ b,
                               float* __restrict__ p) {
    int t = threadIdx.x;
    A4[blockIdx.x * 256 + t] = make_float4(0.f, 0.f, 0.f, 0.f);
    if (blockIdx.x < 256) {
        int wid = t >> 6, lane = t & 63;
        int node = blockIdx.x * 4 + wid;
        const float* f = feat + node * INDIM;
        float s = f[lane] * w[lane] + f[lane + 64] * w[lane + 64];
#pragma unroll
        for (int off = 32; off; off >>= 1) s += __shfl_down(s, off);
        if (lane == 0) p[node] = s + b[0];
    }
}

__global__ void build_A_kernel(const int* __restrict__ eu, const int* __restrict__ ev,
                               const float* __restrict__ p, float* __restrict__ A) {
    int i = blockIdx.x * blockDim.x + threadIdx.x;
    if (i >= NEDGE) return;
    int u = eu[i], v = ev[i];
    float val = p[u] - p[v];
    if (val > 0.f) {
        float w = 1.f + val;
        atomicAdd(&A[u * NPTS + v], w);
        atomicAdd(&A[v * NPTS + u], w);
    } else {
        atomicAdd(&A[u * NPTS + u], 1.f);
        atomicAdd(&A[v * NPTS + v], 1.f);
    }
}

// wave per row: dinv[row] = rsqrt(1 + sum_j A[row][j])   (+1 = the eye)
__global__ void row_deg_kernel(const float* __restrict__ A, float* __restrict__ dinv) {
    int wid = threadIdx.x >> 6, lane = threadIdx.x & 63;
    int row = blockIdx.x * 4 + wid;
    const float4* r4 = (const float4*)(A + (size_t)row * NPTS);
    float s = 0.f;
#pragma unroll
    for (int c = 0; c < 4; ++c) {
        float4 v = r4[c * 64 + lane];
        s += v.x + v.y + v.z + v.w;
    }
#pragma unroll
    for (int off = 32; off; off >>= 1) s += __shfl_down(s, off);
    if (lane == 0) dinv[row] = rsqrtf(s + 1.f);
}

// per float4: T0 = I, T1 = M = -(dinv_i*(A+I)_ij*dinv_j), Mbf = bf16(M)
__global__ void normalize_kernel(const float* __restrict__ A, const float* __restrict__ dinv,
                                 float* __restrict__ out, ushort* __restrict__ Mbf) {
    int idx4 = blockIdx.x * blockDim.x + threadIdx.x;   // 0 .. NN/4
    int i = idx4 >> 8;
    int j = (idx4 & 255) * 4;
    size_t idx = (size_t)idx4 * 4;
    float di = dinv[i];
    float4 a = *(const float4*)(A + idx);
    float4 dj = *(const float4*)(dinv + j);
    float4 t0 = make_float4(0.f, 0.f, 0.f, 0.f);
    if (i == j) t0.x = 1.f;
    else if (i == j + 1) t0.y = 1.f;
    else if (i == j + 2) t0.z = 1.f;
    else if (i == j + 3) t0.w = 1.f;
    // fold eye into A
    a.x += (i == j);
    a.y += (i == j + 1);
    a.z += (i == j + 2);
    a.w += (i == j + 3);
    float4 m;
    m.x = -(di * a.x * dj.x);
    m.y = -(di * a.y * dj.y);
    m.z = -(di * a.z * dj.z);
    m.w = -(di * a.w * dj.w);
    *(float4*)(out + idx) = t0;
    *(float4*)(out + NN + idx) = m;
    ushort mb[4] = {f2bf(m.x), f2bf(m.y), f2bf(m.z), f2bf(m.w)};
    *(uint2*)(Mbf + idx) = *(uint2*)mb;
}

// ---------------- MFMA GEMM (bf16 in, fp32 acc) ----------------
// 64x64 tile / block, 4 waves of 32x32 (2x2 of 16x16x32 MFMA), BK=64.
// All operands symmetric -> B read row-wise.
// phase 0:            S = M*M -> T2 = 2S - I,  Sbf = bf16(S)
// phase 1, z=0:       P = S*S -> T4 = 8P - 4*T2 - 3I
// phase 1, z=1:       R = M*S -> T3 = 4R - 3*T1
__global__ __launch_bounds__(256) void cheb_mfma_kernel(const ushort* __restrict__ Mbf,
                                                        const ushort* __restrict__ Sbf,
                                                        float* __restrict__ out,
                                                        int phase, int zimag) {
    int mode = (phase == 0) ? 1 : (2 + blockIdx.z);

    // hidden zeroing of the imag half (20 MB spread over 512 blocks)
    if (phase == 1 && zimag) {
        int bid = blockIdx.z * 256 + blockIdx.y * 16 + blockIdx.x;
        float4* z = (float4*)(out + (size_t)5 * NN) + (size_t)bid * 2560 + threadIdx.x;
#pragma unroll
        for (int i = 0; i < 10; ++i) z[i * 256] = make_float4(0.f, 0.f, 0.f, 0.f);
    }

    const ushort* Ab = (mode == 2) ? Sbf : Mbf;
    const ushort* Bb = (mode == 1) ? Mbf : Sbf;

    __shared__ __align__(16) ushort sA[64][72];
    __shared__ __align__(16) ushort sB[64][72];

    int tid = threadIdx.x;
    int brow = blockIdx.y * 64, bcol = blockIdx.x * 64;

    int r0 = tid >> 3;            // 0..31
    int j0 = (tid & 7) * 8;       // 0..56 (bf16 units, 16B aligned)
    int r1 = r0 + 32;

    int wid = tid >> 6, lane = tid & 63;
    int wr = (wid >> 1) * 32, wc = (wid & 1) * 32;
    int fr = lane & 15, g = lane >> 4;

    f32x4 acc[2][2] = {};
    float4 pa0, pa1, pb0, pb1;

    pa0 = *(const float4*)(Ab + (size_t)(brow + r0) * NPTS + j0);
    pa1 = *(const float4*)(Ab + (size_t)(brow + r1) * NPTS + j0);
    pb0 = *(const float4*)(Bb + (size_t)(bcol + r0) * NPTS + j0);
    pb1 = *(const float4*)(Bb + (size_t)(bcol + r1) * NPTS + j0);

    const int NT = NPTS / 64;
    for (int t = 0; t < NT; ++t) {
        __syncthreads();
        *(float4*)&sA[r0][j0] = pa0;
        *(float4*)&sA[r1][j0] = pa1;
        *(float4*)&sB[r0][j0] = pb0;
        *(float4*)&sB[r1][j0] = pb1;
        __syncthreads();
        if (t + 1 < NT) {
            int k0 = (t + 1) * 64;
            pa0 = *(const float4*)(Ab + (size_t)(brow + r0) * NPTS + k0 + j0);
            pa1 = *(const float4*)(Ab + (size_t)(brow + r1) * NPTS + k0 + j0);
            pb0 = *(const float4*)(Bb + (size_t)(bcol + r0) * NPTS + k0 + j0);
            pb1 = *(const float4*)(Bb + (size_t)(bcol + r1) * NPTS + k0 + j0);
        }
#pragma unroll
        for (int kc = 0; kc < 2; ++kc) {
            int kk = kc * 32 + g * 8;
            bf16x8 a0 = *(const bf16x8*)&sA[wr + fr][kk];
            bf16x8 a1 = *(const bf16x8*)&sA[wr + 16 + fr][kk];
            bf16x8 b0 = *(const bf16x8*)&sB[wc + fr][kk];
            bf16x8 b1 = *(const bf16x8*)&sB[wc + 16 + fr][kk];
            acc[0][0] = __builtin_amdgcn_mfma_f32_16x16x32_bf16(a0, b0, acc[0][0], 0, 0, 0);
            acc[0][1] = __builtin_amdgcn_mfma_f32_16x16x32_bf16(a0, b1, acc[0][1], 0, 0, 0);
            acc[1][0] = __builtin_amdgcn_mfma_f32_16x16x32_bf16(a1, b0, acc[1][0], 0, 0, 0);
            acc[1][1] = __builtin_amdgcn_mfma_f32_16x16x32_bf16(a1, b1, acc[1][1], 0, 0, 0);
        }
    }

    float* T1 = out + (size_t)NN;
    float* T2 = out + (size_t)2 * NN;
    float* T3 = out + (size_t)3 * NN;
    float* T4 = out + (size_t)4 * NN;
    ushort* SbfW = (ushort*)Sbf;

#pragma unroll
    for (int mi = 0; mi < 2; ++mi) {
#pragma unroll
        for (int ni = 0; ni < 2; ++ni) {
#pragma unroll
            for (int q = 0; q < 4; ++q) {
                int row = brow + wr + mi * 16 + g * 4 + q;
                int col = bcol + wc + ni * 16 + fr;
                size_t idx = (size_t)row * NPTS + col;
                float s = acc[mi][ni][q];
                if (mode == 1) {
                    T2[idx] = 2.f * s - (row == col ? 1.f : 0.f);
                    SbfW[idx] = f2bf(s);
                } else if (mode == 2) {
                    T4[idx] = 8.f * s - 4.f * T2[idx] - (row == col ? 3.f : 0.f);
                } else {
                    T3[idx] = 4.f * s - 3.f * T1[idx];
                }
            }
        }
    }
}

__global__ void zero_kernel(float4* __restrict__ p, int n4) {
    int i = blockIdx.x * blockDim.x + threadIdx.x;
    if (i < n4) p[i] = make_float4(0.f, 0.f, 0.f, 0.f);
}

// ---------------- launch ----------------

extern "C" void kernel_launch(void* const* d_in, const int* in_sizes, int n_in,
                              void* d_out, int out_size, void* d_ws, size_t ws_size,
                              hipStream_t stream) {
    const float* feat = (const float*)d_in[0];
    const int* edges = (const int*)d_in[1];
    const float* w_e1 = (const float*)d_in[2];
    const float* b_e1 = (const float*)d_in[3];
    float* out = (float*)d_out;

    // scratch layout (prefer d_ws; fallback = imag half of out)
    const size_t need = (size_t)NN * 4 /*A*/ + (size_t)NN * 2 /*Mbf*/ +
                        (size_t)NN * 2 /*Sbf*/ + NPTS * 8 + 256;
    float* A;
    ushort* Mbf;
    ushort* Sbf;
    float* p;
    float* dinv;
    int use_ws = (ws_size >= need);
    if (use_ws) {
        char* w = (char*)d_ws;
        A = (float*)w;                       w += (size_t)NN * 4;
        Mbf = (ushort*)w;                    w += (size_t)NN * 2;
        Sbf = (ushort*)w;                    w += (size_t)NN * 2;
        p = (float*)w;                       w += NPTS * 4;
        dinv = (float*)w;
    } else {
        A = out + (size_t)5 * NN;
        Mbf = (ushort*)(out + (size_t)6 * NN);
        Sbf = Mbf + NN;
        p = out + (size_t)7 * NN;
        dinv = p + NPTS;
    }

    zeroA_p_kernel<<<1024, 256, 0, stream>>>((float4*)A, feat, w_e1, b_e1, p);
    build_A_kernel<<<(NEDGE + 255) / 256, 256, 0, stream>>>(edges, edges + NEDGE, p, A);
    row_deg_kernel<<<256, 256, 0, stream>>>(A, dinv);
    normalize_kernel<<<NN / 4 / 256, 256, 0, stream>>>(A, dinv, out, Mbf);

    dim3 grid1(16, 16, 1);
    cheb_mfma_kernel<<<grid1, 256, 0, stream>>>(Mbf, Sbf, out, 0, 0);
    dim3 grid2(16, 16, 2);
    cheb_mfma_kernel<<<grid2, 256, 0, stream>>>(Mbf, Sbf, out, 1, use_ws);

    if (!use_ws) {
        zero_kernel<<<(5 * NN / 4 + 255) / 256, 256, 0, stream>>>(
            (float4*)(out + (size_t)5 * NN), 5 * NN / 4);
    }
}

// Round 4
// 48.516 us; speedup vs baseline: 5.5679x; 1.1160x over previous
//
#include <hip/hip_runtime.h>

#define NPTS 1024
#define NN (NPTS * NPTS)
#define NEDGE 32768
#define INDIM 128

typedef __attribute__((ext_vector_type(8))) short bf16x8;
typedef __attribute__((ext_vector_type(4))) float f32x4;

__device__ inline ushort f2bf(float x) {
    union { float f; unsigned u; } v; v.f = x;
    unsigned r = (v.u + 0x7FFF + ((v.u >> 16) & 1)) >> 16;
    return (ushort)r;
}

// ---------------- front-end kernels ----------------

// grid 1024 x 256: every block zeroes 256 float4 of A; blocks 0..255 also
// compute p for 4 nodes (one wave each).
__global__ void zeroA_p_kernel(float4* __restrict__ A4,
                               const float* __restrict__ feat,
                               const float* __restrict__ w,
                               const float* __restrict__ b,
                               float* __restrict__ p) {
    int t = threadIdx.x;
    A4[blockIdx.x * 256 + t] = make_float4(0.f, 0.f, 0.f, 0.f);
    if (blockIdx.x < 256) {
        int wid = t >> 6, lane = t & 63;
        int node = blockIdx.x * 4 + wid;
        const float* f = feat + node * INDIM;
        float s = f[lane] * w[lane] + f[lane + 64] * w[lane + 64];
#pragma unroll
        for (int off = 32; off; off >>= 1) s += __shfl_down(s, off);
        if (lane == 0) p[node] = s + b[0];
    }
}

__global__ void build_A_kernel(const int* __restrict__ eu, const int* __restrict__ ev,
                               const float* __restrict__ p, float* __restrict__ A) {
    int i = blockIdx.x * blockDim.x + threadIdx.x;
    if (i >= NEDGE) return;
    int u = eu[i], v = ev[i];
    float val = p[u] - p[v];
    if (val > 0.f) {
        float w = 1.f + val;
        atomicAdd(&A[u * NPTS + v], w);
        atomicAdd(&A[v * NPTS + u], w);
    } else {
        atomicAdd(&A[u * NPTS + u], 1.f);
        atomicAdd(&A[v * NPTS + v], 1.f);
    }
}

// wave per row: dinv[row] = rsqrt(1 + sum_j A[row][j])   (+1 = the eye)
__global__ void row_deg_kernel(const float* __restrict__ A, float* __restrict__ dinv) {
    int wid = threadIdx.x >> 6, lane = threadIdx.x & 63;
    int row = blockIdx.x * 4 + wid;
    const float4* r4 = (const float4*)(A + (size_t)row * NPTS);
    float s = 0.f;
#pragma unroll
    for (int c = 0; c < 4; ++c) {
        float4 v = r4[c * 64 + lane];
        s += v.x + v.y + v.z + v.w;
    }
#pragma unroll
    for (int off = 32; off; off >>= 1) s += __shfl_down(s, off);
    if (lane == 0) dinv[row] = rsqrtf(s + 1.f);
}

// per float4: T0 = I, T1 = M = -(dinv_i*(A+I)_ij*dinv_j), Mbf = bf16(M)
__global__ void normalize_kernel(const float* __restrict__ A, const float* __restrict__ dinv,
                                 float* __restrict__ out, ushort* __restrict__ Mbf) {
    int idx4 = blockIdx.x * blockDim.x + threadIdx.x;   // 0 .. NN/4
    int i = idx4 >> 8;
    int j = (idx4 & 255) * 4;
    size_t idx = (size_t)idx4 * 4;
    float di = dinv[i];
    float4 a = *(const float4*)(A + idx);
    float4 dj = *(const float4*)(dinv + j);
    float4 t0 = make_float4(0.f, 0.f, 0.f, 0.f);
    if (i == j) t0.x = 1.f;
    else if (i == j + 1) t0.y = 1.f;
    else if (i == j + 2) t0.z = 1.f;
    else if (i == j + 3) t0.w = 1.f;
    a.x += (i == j);
    a.y += (i == j + 1);
    a.z += (i == j + 2);
    a.w += (i == j + 3);
    float4 m;
    m.x = -(di * a.x * dj.x);
    m.y = -(di * a.y * dj.y);
    m.z = -(di * a.z * dj.z);
    m.w = -(di * a.w * dj.w);
    *(float4*)(out + idx) = t0;
    *(float4*)(out + NN + idx) = m;
    ushort mb[4] = {f2bf(m.x), f2bf(m.y), f2bf(m.z), f2bf(m.w)};
    *(uint2*)(Mbf + idx) = *(uint2*)mb;
}

// ---------------- MFMA GEMM (bf16 in, fp32 acc) ----------------
// 64x64 tile / block, 512 threads = 8 waves (2 waves/SIMD for latency hiding).
// Wave (wid) owns 16 rows x 32 cols: wr=(wid&3)*16, wc=(wid>>2)*32.
// Per kc(32): 1 A-frag + 2 B-frags (ds_read_b128), 2 x mfma_f32_16x16x32_bf16.
// All operands symmetric -> B read row-wise.
// phase 0:            S = M*M -> T2 = 2S - I,  Sbf = bf16(S)
// phase 1, z=0:       P = S*S -> T4 = 8P - 4*T2 - 3I
// phase 1, z=1:       R = M*S -> T3 = 4R - 3*T1
__global__ __launch_bounds__(512) void cheb_mfma_kernel(const ushort* __restrict__ Mbf,
                                                        const ushort* __restrict__ Sbf,
                                                        float* __restrict__ out,
                                                        int phase, int zimag) {
    int mode = (phase == 0) ? 1 : (2 + blockIdx.z);

    // hidden zeroing of the imag half (20 MB spread over 512 blocks)
    if (phase == 1 && zimag) {
        int bid = blockIdx.z * 256 + blockIdx.y * 16 + blockIdx.x;
        float4* z = (float4*)(out + (size_t)5 * NN) + (size_t)bid * 2560 + threadIdx.x;
#pragma unroll
        for (int i = 0; i < 5; ++i) z[i * 512] = make_float4(0.f, 0.f, 0.f, 0.f);
    }

    const ushort* Ab = (mode == 2) ? Sbf : Mbf;
    const ushort* Bb = (mode == 1) ? Mbf : Sbf;

    __shared__ __align__(16) ushort sA[64][72];
    __shared__ __align__(16) ushort sB[64][72];

    int tid = threadIdx.x;
    int brow = blockIdx.y * 64, bcol = blockIdx.x * 64;

    int r = tid >> 3;             // 0..63
    int j0 = (tid & 7) * 8;       // 0..56 (bf16 units, 16B aligned)

    int wid = tid >> 6, lane = tid & 63;
    int wr = (wid & 3) * 16, wc = (wid >> 2) * 32;
    int fr = lane & 15, g = lane >> 4;

    f32x4 acc[2] = {};
    float4 pa, pb;

    pa = *(const float4*)(Ab + (size_t)(brow + r) * NPTS + j0);
    pb = *(const float4*)(Bb + (size_t)(bcol + r) * NPTS + j0);

    const int NT = NPTS / 64;
    for (int t = 0; t < NT; ++t) {
        __syncthreads();
        *(float4*)&sA[r][j0] = pa;
        *(float4*)&sB[r][j0] = pb;
        __syncthreads();
        if (t + 1 < NT) {
            int k0 = (t + 1) * 64;
            pa = *(const float4*)(Ab + (size_t)(brow + r) * NPTS + k0 + j0);
            pb = *(const float4*)(Bb + (size_t)(bcol + r) * NPTS + k0 + j0);
        }
#pragma unroll
        for (int kc = 0; kc < 2; ++kc) {
            int kk = kc * 32 + g * 8;
            bf16x8 a0 = *(const bf16x8*)&sA[wr + fr][kk];
            bf16x8 b0 = *(const bf16x8*)&sB[wc + fr][kk];
            bf16x8 b1 = *(const bf16x8*)&sB[wc + 16 + fr][kk];
            acc[0] = __builtin_amdgcn_mfma_f32_16x16x32_bf16(a0, b0, acc[0], 0, 0, 0);
            acc[1] = __builtin_amdgcn_mfma_f32_16x16x32_bf16(a0, b1, acc[1], 0, 0, 0);
        }
    }

    float* T1 = out + (size_t)NN;
    float* T2 = out + (size_t)2 * NN;
    float* T3 = out + (size_t)3 * NN;
    float* T4 = out + (size_t)4 * NN;
    ushort* SbfW = (ushort*)Sbf;

#pragma unroll
    for (int ni = 0; ni < 2; ++ni) {
#pragma unroll
        for (int q = 0; q < 4; ++q) {
            int row = brow + wr + g * 4 + q;
            int col = bcol + wc + ni * 16 + fr;
            size_t idx = (size_t)row * NPTS + col;
            float s = acc[ni][q];
            if (mode == 1) {
                T2[idx] = 2.f * s - (row == col ? 1.f : 0.f);
                SbfW[idx] = f2bf(s);
            } else if (mode == 2) {
                T4[idx] = 8.f * s - 4.f * T2[idx] - (row == col ? 3.f : 0.f);
            } else {
                T3[idx] = 4.f * s - 3.f * T1[idx];
            }
        }
    }
}

__global__ void zero_kernel(float4* __restrict__ p, int n4) {
    int i = blockIdx.x * blockDim.x + threadIdx.x;
    if (i < n4) p[i] = make_float4(0.f, 0.f, 0.f, 0.f);
}

// ---------------- launch ----------------

extern "C" void kernel_launch(void* const* d_in, const int* in_sizes, int n_in,
                              void* d_out, int out_size, void* d_ws, size_t ws_size,
                              hipStream_t stream) {
    const float* feat = (const float*)d_in[0];
    const int* edges = (const int*)d_in[1];
    const float* w_e1 = (const float*)d_in[2];
    const float* b_e1 = (const float*)d_in[3];
    float* out = (float*)d_out;

    // scratch layout (prefer d_ws; fallback = imag half of out)
    const size_t need = (size_t)NN * 4 /*A*/ + (size_t)NN * 2 /*Mbf*/ +
                        (size_t)NN * 2 /*Sbf*/ + NPTS * 8 + 256;
    float* A;
    ushort* Mbf;
    ushort* Sbf;
    float* p;
    float* dinv;
    int use_ws = (ws_size >= need);
    if (use_ws) {
        char* w = (char*)d_ws;
        A = (float*)w;                       w += (size_t)NN * 4;
        Mbf = (ushort*)w;                    w += (size_t)NN * 2;
        Sbf = (ushort*)w;                    w += (size_t)NN * 2;
        p = (float*)w;                       w += NPTS * 4;
        dinv = (float*)w;
    } else {
        A = out + (size_t)5 * NN;
        Mbf = (ushort*)(out + (size_t)6 * NN);
        Sbf = Mbf + NN;
        p = out + (size_t)7 * NN;
        dinv = p + NPTS;
    }

    zeroA_p_kernel<<<1024, 256, 0, stream>>>((float4*)A, feat, w_e1, b_e1, p);
    build_A_kernel<<<(NEDGE + 255) / 256, 256, 0, stream>>>(edges, edges + NEDGE, p, A);
    row_deg_kernel<<<256, 256, 0, stream>>>(A, dinv);
    normalize_kernel<<<NN / 4 / 256, 256, 0, stream>>>(A, dinv, out, Mbf);

    dim3 grid1(16, 16, 1);
    cheb_mfma_kernel<<<grid1, 512, 0, stream>>>(Mbf, Sbf, out, 0, 0);
    dim3 grid2(16, 16, 2);
    cheb_mfma_kernel<<<grid2, 512, 0, stream>>>(Mbf, Sbf, out, 1, use_ws);

    if (!use_ws) {
        zero_kernel<<<(5 * NN / 4 + 255) / 256, 256, 0, stream>>>(
            (float4*)(out + (size_t)5 * NN), 5 * NN / 4);
    }
}

// Round 5
// 48.491 us; speedup vs baseline: 5.5707x; 1.0005x over previous
//
#include <hip/hip_runtime.h>

#define NPTS 1024
#define NN (NPTS * NPTS)
#define NEDGE 32768
#define INDIM 128
#define PAD 72

typedef __attribute__((ext_vector_type(8))) short bf16x8;
typedef __attribute__((ext_vector_type(4))) float f32x4;

__device__ inline ushort f2bf(float x) {
    union { float f; unsigned u; } v; v.f = x;
    unsigned r = (v.u + 0x7FFF + ((v.u >> 16) & 1)) >> 16;
    return (ushort)r;
}

#define MFMA(a, b, c) __builtin_amdgcn_mfma_f32_16x16x32_bf16(a, b, c, 0, 0, 0)

// ---------------- front-end kernels ----------------

__global__ void zeroA_p_kernel(float4* __restrict__ A4,
                               const float* __restrict__ feat,
                               const float* __restrict__ w,
                               const float* __restrict__ b,
                               float* __restrict__ p) {
    int t = threadIdx.x;
    A4[blockIdx.x * 256 + t] = make_float4(0.f, 0.f, 0.f, 0.f);
    if (blockIdx.x < 256) {
        int wid = t >> 6, lane = t & 63;
        int node = blockIdx.x * 4 + wid;
        const float* f = feat + node * INDIM;
        float s = f[lane] * w[lane] + f[lane + 64] * w[lane + 64];
#pragma unroll
        for (int off = 32; off; off >>= 1) s += __shfl_down(s, off);
        if (lane == 0) p[node] = s + b[0];
    }
}

__global__ void build_A_kernel(const int* __restrict__ eu, const int* __restrict__ ev,
                               const float* __restrict__ p, float* __restrict__ A) {
    int i = blockIdx.x * blockDim.x + threadIdx.x;
    if (i >= NEDGE) return;
    int u = eu[i], v = ev[i];
    float val = p[u] - p[v];
    if (val > 0.f) {
        float w = 1.f + val;
        atomicAdd(&A[u * NPTS + v], w);
        atomicAdd(&A[v * NPTS + u], w);
    } else {
        atomicAdd(&A[u * NPTS + u], 1.f);
        atomicAdd(&A[v * NPTS + v], 1.f);
    }
}

__global__ void row_deg_kernel(const float* __restrict__ A, float* __restrict__ dinv) {
    int wid = threadIdx.x >> 6, lane = threadIdx.x & 63;
    int row = blockIdx.x * 4 + wid;
    const float4* r4 = (const float4*)(A + (size_t)row * NPTS);
    float s = 0.f;
#pragma unroll
    for (int c = 0; c < 4; ++c) {
        float4 v = r4[c * 64 + lane];
        s += v.x + v.y + v.z + v.w;
    }
#pragma unroll
    for (int off = 32; off; off >>= 1) s += __shfl_down(s, off);
    if (lane == 0) dinv[row] = rsqrtf(s + 1.f);
}

__global__ void normalize_kernel(const float* __restrict__ A, const float* __restrict__ dinv,
                                 float* __restrict__ out, ushort* __restrict__ Mbf) {
    int idx4 = blockIdx.x * blockDim.x + threadIdx.x;
    int i = idx4 >> 8;
    int j = (idx4 & 255) * 4;
    size_t idx = (size_t)idx4 * 4;
    float di = dinv[i];
    float4 a = *(const float4*)(A + idx);
    float4 dj = *(const float4*)(dinv + j);
    float4 t0 = make_float4(0.f, 0.f, 0.f, 0.f);
    if (i == j) t0.x = 1.f;
    else if (i == j + 1) t0.y = 1.f;
    else if (i == j + 2) t0.z = 1.f;
    else if (i == j + 3) t0.w = 1.f;
    a.x += (i == j);
    a.y += (i == j + 1);
    a.z += (i == j + 2);
    a.w += (i == j + 3);
    float4 m;
    m.x = -(di * a.x * dj.x);
    m.y = -(di * a.y * dj.y);
    m.z = -(di * a.z * dj.z);
    m.w = -(di * a.w * dj.w);
    *(float4*)(out + idx) = t0;
    *(float4*)(out + NN + idx) = m;
    ushort mb[4] = {f2bf(m.x), f2bf(m.y), f2bf(m.z), f2bf(m.w)};
    *(uint2*)(Mbf + idx) = *(uint2*)mb;
}

// ---------------- phase 0: S = M*M -> T2 = 2S - I, Sbf ----------------
// 64x64 tile, 512 thr = 8 waves. Split-K: BK=128 staged as 2 sub-buffers;
// wave group h=wid>>2 consumes sub-buffer h. Each wave: 32x32 via 2x2 frags.
// Partial sums combined via 16KB LDS reduction (group 1 -> group 0).
__global__ __launch_bounds__(512) void gemm_S_kernel(const ushort* __restrict__ Mbf,
                                                     ushort* __restrict__ Sbf,
                                                     float* __restrict__ out) {
    __shared__ __align__(16) ushort smem[4 * 64 * PAD];  // 36.9 KB
    ushort(*sA)[64][PAD] = (ushort(*)[64][PAD])smem;
    ushort(*sB)[64][PAD] = (ushort(*)[64][PAD])(smem + 2 * 64 * PAD);
    float* red = (float*)smem;  // 16 KB reduction region (aliases sA)

    int tid = threadIdx.x;
    int brow = blockIdx.y * 64, bcol = blockIdx.x * 64;
    int r = tid >> 3, j0 = (tid & 7) * 8;
    int wid = tid >> 6, lane = tid & 63;
    int h = wid >> 2, w4 = wid & 3;
    int wr = (w4 & 1) * 32, wc = (w4 >> 1) * 32;
    int fr = lane & 15, g = lane >> 4;

    const ushort* Arow = Mbf + (size_t)(brow + r) * NPTS;
    const ushort* Brow = Mbf + (size_t)(bcol + r) * NPTS;

    f32x4 acc[2][2] = {};
    float4 pa0 = *(const float4*)(Arow + j0);
    float4 pa1 = *(const float4*)(Arow + 64 + j0);
    float4 pb0 = *(const float4*)(Brow + j0);
    float4 pb1 = *(const float4*)(Brow + 64 + j0);

    for (int it = 0; it < 8; ++it) {
        __syncthreads();
        *(float4*)&sA[0][r][j0] = pa0;
        *(float4*)&sA[1][r][j0] = pa1;
        *(float4*)&sB[0][r][j0] = pb0;
        *(float4*)&sB[1][r][j0] = pb1;
        __syncthreads();
        if (it < 7) {
            int k0 = (it + 1) * 128;
            pa0 = *(const float4*)(Arow + k0 + j0);
            pa1 = *(const float4*)(Arow + k0 + 64 + j0);
            pb0 = *(const float4*)(Brow + k0 + j0);
            pb1 = *(const float4*)(Brow + k0 + 64 + j0);
        }
#pragma unroll
        for (int kc = 0; kc < 2; ++kc) {
            int kk = kc * 32 + g * 8;
            bf16x8 a0 = *(const bf16x8*)&sA[h][wr + fr][kk];
            bf16x8 a1 = *(const bf16x8*)&sA[h][wr + 16 + fr][kk];
            bf16x8 b0 = *(const bf16x8*)&sB[h][wc + fr][kk];
            bf16x8 b1 = *(const bf16x8*)&sB[h][wc + 16 + fr][kk];
            acc[0][0] = MFMA(a0, b0, acc[0][0]);
            acc[0][1] = MFMA(a0, b1, acc[0][1]);
            acc[1][0] = MFMA(a1, b0, acc[1][0]);
            acc[1][1] = MFMA(a1, b1, acc[1][1]);
        }
    }

    __syncthreads();  // all reads of sA/sB done
    if (h == 1) {
#pragma unroll
        for (int q = 0; q < 4; ++q)
            *(f32x4*)&red[q * 1024 + (w4 * 64 + lane) * 4] = acc[q >> 1][q & 1];
    }
    __syncthreads();
    if (h == 0) {
        float* T2 = out + (size_t)2 * NN;
#pragma unroll
        for (int mi = 0; mi < 2; ++mi) {
#pragma unroll
            for (int ni = 0; ni < 2; ++ni) {
                f32x4 o = *(f32x4*)&red[(mi * 2 + ni) * 1024 + (w4 * 64 + lane) * 4];
#pragma unroll
                for (int q = 0; q < 4; ++q) {
                    int row = brow + wr + mi * 16 + g * 4 + q;
                    int col = bcol + wc + ni * 16 + fr;
                    size_t idx = (size_t)row * NPTS + col;
                    float s = acc[mi][ni][q] + o[q];
                    T2[idx] = 2.f * s - (row == col ? 1.f : 0.f);
                    Sbf[idx] = f2bf(s);
                }
            }
        }
    }
}

// ---------------- phase 1 (fused): P = S*S -> T4, R = M*S -> T3 ----------------
// Same split-K structure; 3 staged operands (S-rows, M-rows, S-cols); the
// B-frags are shared by both products: 6 ds_reads per 8 MFMA.
__global__ __launch_bounds__(512) void gemm_T34_kernel(const ushort* __restrict__ Mbf,
                                                       const ushort* __restrict__ Sbf,
                                                       float* __restrict__ out,
                                                       int zimag) {
    // hidden zeroing of the imag half (20 MB over 256 blocks)
    if (zimag) {
        int bid = blockIdx.y * 16 + blockIdx.x;
        float4* z = (float4*)(out + (size_t)5 * NN) + (size_t)bid * 5120 + threadIdx.x;
#pragma unroll
        for (int i = 0; i < 10; ++i) z[i * 512] = make_float4(0.f, 0.f, 0.f, 0.f);
    }

    __shared__ __align__(16) ushort smem[6 * 64 * PAD];  // 55.3 KB
    ushort(*sAS)[64][PAD] = (ushort(*)[64][PAD])smem;
    ushort(*sAM)[64][PAD] = (ushort(*)[64][PAD])(smem + 2 * 64 * PAD);
    ushort(*sB)[64][PAD] = (ushort(*)[64][PAD])(smem + 4 * 64 * PAD);
    float* red = (float*)smem;  // 32 KB reduction region

    int tid = threadIdx.x;
    int brow = blockIdx.y * 64, bcol = blockIdx.x * 64;
    int r = tid >> 3, j0 = (tid & 7) * 8;
    int wid = tid >> 6, lane = tid & 63;
    int h = wid >> 2, w4 = wid & 3;
    int wr = (w4 & 1) * 32, wc = (w4 >> 1) * 32;
    int fr = lane & 15, g = lane >> 4;

    const ushort* ASrow = Sbf + (size_t)(brow + r) * NPTS;
    const ushort* AMrow = Mbf + (size_t)(brow + r) * NPTS;
    const ushort* Brow = Sbf + (size_t)(bcol + r) * NPTS;

    f32x4 accP[2][2] = {};
    f32x4 accR[2][2] = {};
    float4 ps0 = *(const float4*)(ASrow + j0);
    float4 ps1 = *(const float4*)(ASrow + 64 + j0);
    float4 pm0 = *(const float4*)(AMrow + j0);
    float4 pm1 = *(const float4*)(AMrow + 64 + j0);
    float4 pb0 = *(const float4*)(Brow + j0);
    float4 pb1 = *(const float4*)(Brow + 64 + j0);

    for (int it = 0; it < 8; ++it) {
        __syncthreads();
        *(float4*)&sAS[0][r][j0] = ps0;
        *(float4*)&sAS[1][r][j0] = ps1;
        *(float4*)&sAM[0][r][j0] = pm0;
        *(float4*)&sAM[1][r][j0] = pm1;
        *(float4*)&sB[0][r][j0] = pb0;
        *(float4*)&sB[1][r][j0] = pb1;
        __syncthreads();
        if (it < 7) {
            int k0 = (it + 1) * 128;
            ps0 = *(const float4*)(ASrow + k0 + j0);
            ps1 = *(const float4*)(ASrow + k0 + 64 + j0);
            pm0 = *(const float4*)(AMrow + k0 + j0);
            pm1 = *(const float4*)(AMrow + k0 + 64 + j0);
            pb0 = *(const float4*)(Brow + k0 + j0);
            pb1 = *(const float4*)(Brow + k0 + 64 + j0);
        }
#pragma unroll
        for (int kc = 0; kc < 2; ++kc) {
            int kk = kc * 32 + g * 8;
            bf16x8 b0 = *(const bf16x8*)&sB[h][wc + fr][kk];
            bf16x8 b1 = *(const bf16x8*)&sB[h][wc + 16 + fr][kk];
            bf16x8 s0 = *(const bf16x8*)&sAS[h][wr + fr][kk];
            bf16x8 s1 = *(const bf16x8*)&sAS[h][wr + 16 + fr][kk];
            accP[0][0] = MFMA(s0, b0, accP[0][0]);
            accP[0][1] = MFMA(s0, b1, accP[0][1]);
            accP[1][0] = MFMA(s1, b0, accP[1][0]);
            accP[1][1] = MFMA(s1, b1, accP[1][1]);
            bf16x8 m0 = *(const bf16x8*)&sAM[h][wr + fr][kk];
            bf16x8 m1 = *(const bf16x8*)&sAM[h][wr + 16 + fr][kk];
            accR[0][0] = MFMA(m0, b0, accR[0][0]);
            accR[0][1] = MFMA(m0, b1, accR[0][1]);
            accR[1][0] = MFMA(m1, b0, accR[1][0]);
            accR[1][1] = MFMA(m1, b1, accR[1][1]);
        }
    }

    __syncthreads();
    if (h == 1) {
#pragma unroll
        for (int q = 0; q < 4; ++q) {
            *(f32x4*)&red[q * 1024 + (w4 * 64 + lane) * 4] = accP[q >> 1][q & 1];
            *(f32x4*)&red[4096 + q * 1024 + (w4 * 64 + lane) * 4] = accR[q >> 1][q & 1];
        }
    }
    __syncthreads();
    if (h == 0) {
        float* T1 = out + (size_t)NN;
        float* T2 = out + (size_t)2 * NN;
        float* T3 = out + (size_t)3 * NN;
        float* T4 = out + (size_t)4 * NN;
#pragma unroll
        for (int mi = 0; mi < 2; ++mi) {
#pragma unroll
            for (int ni = 0; ni < 2; ++ni) {
                f32x4 oP = *(f32x4*)&red[(mi * 2 + ni) * 1024 + (w4 * 64 + lane) * 4];
                f32x4 oR = *(f32x4*)&red[4096 + (mi * 2 + ni) * 1024 + (w4 * 64 + lane) * 4];
#pragma unroll
                for (int q = 0; q < 4; ++q) {
                    int row = brow + wr + mi * 16 + g * 4 + q;
                    int col = bcol + wc + ni * 16 + fr;
                    size_t idx = (size_t)row * NPTS + col;
                    float sp = accP[mi][ni][q] + oP[q];
                    float sr = accR[mi][ni][q] + oR[q];
                    T4[idx] = 8.f * sp - 4.f * T2[idx] - (row == col ? 3.f : 0.f);
                    T3[idx] = 4.f * sr - 3.f * T1[idx];
                }
            }
        }
    }
}

__global__ void zero_kernel(float4* __restrict__ p, int n4) {
    int i = blockIdx.x * blockDim.x + threadIdx.x;
    if (i < n4) p[i] = make_float4(0.f, 0.f, 0.f, 0.f);
}

// ---------------- launch ----------------

extern "C" void kernel_launch(void* const* d_in, const int* in_sizes, int n_in,
                              void* d_out, int out_size, void* d_ws, size_t ws_size,
                              hipStream_t stream) {
    const float* feat = (const float*)d_in[0];
    const int* edges = (const int*)d_in[1];
    const float* w_e1 = (const float*)d_in[2];
    const float* b_e1 = (const float*)d_in[3];
    float* out = (float*)d_out;

    const size_t need = (size_t)NN * 4 + (size_t)NN * 2 + (size_t)NN * 2 + NPTS * 8 + 256;
    float* A;
    ushort* Mbf;
    ushort* Sbf;
    float* p;
    float* dinv;
    int use_ws = (ws_size >= need);
    if (use_ws) {
        char* w = (char*)d_ws;
        A = (float*)w;        w += (size_t)NN * 4;
        Mbf = (ushort*)w;     w += (size_t)NN * 2;
        Sbf = (ushort*)w;     w += (size_t)NN * 2;
        p = (float*)w;        w += NPTS * 4;
        dinv = (float*)w;
    } else {
        A = out + (size_t)5 * NN;
        Mbf = (ushort*)(out + (size_t)6 * NN);
        Sbf = Mbf + NN;
        p = out + (size_t)7 * NN;
        dinv = p + NPTS;
    }

    zeroA_p_kernel<<<1024, 256, 0, stream>>>((float4*)A, feat, w_e1, b_e1, p);
    build_A_kernel<<<(NEDGE + 255) / 256, 256, 0, stream>>>(edges, edges + NEDGE, p, A);
    row_deg_kernel<<<256, 256, 0, stream>>>(A, dinv);
    normalize_kernel<<<NN / 4 / 256, 256, 0, stream>>>(A, dinv, out, Mbf);

    dim3 grid(16, 16);
    gemm_S_kernel<<<grid, 512, 0, stream>>>(Mbf, Sbf, out);
    gemm_T34_kernel<<<grid, 512, 0, stream>>>(Mbf, Sbf, out, use_ws);

    if (!use_ws) {
        zero_kernel<<<(5 * NN / 4 + 255) / 256, 256, 0, stream>>>(
            (float4*)(out + (size_t)5 * NN), 5 * NN / 4);
    }
}